// Round 7
// baseline (167.689 us; speedup 1.0000x reference)
//
#include <hip/hip_runtime.h>
#include <hip/hip_bf16.h>
#include <stdint.h>

#define B_ 64
#define S_ 512
#define I_ 256
#define H_ 1024
#define O_ 128
#define M_ (B_*S_)   // 32768

typedef float f32x4 __attribute__((ext_vector_type(4)));
typedef unsigned short u16x4 __attribute__((ext_vector_type(4)));
typedef unsigned short u16x8 __attribute__((ext_vector_type(8)));

__device__ __forceinline__ unsigned short f2bf(float f) {
    unsigned u = __float_as_uint(f);
    u += 0x7FFFu + ((u >> 16) & 1u);
    return (unsigned short)(u >> 16);
}
__device__ __forceinline__ float bf2f(unsigned short s) {
    return __uint_as_float((unsigned)s << 16);
}

// ---- K0: fp32 -> fp8 e4m3 into per-lane fragment order, via LDS transpose.
// A region: [tile128][kq(8)][rb(8)][lane*8B]; B: [hn(16)][kq(8)][rb(4)][lane*8B].
// Fragment: lane l holds row rb*16+(l&15), k = kq*32+(l>>4)*8..+8.
// Block 0 additionally inits firstCross and applies the tau-paranoia guard:
// if the EMA decay is too slow for ks_scan's 64-step warmup bound, force every
// batch onto the exact k3 path (correct for arbitrary tau, slow; never fires
// for the benchmarked tau=2.0 -> gamma=0.881, bound~0.02 << 0.1).
__global__ void __launch_bounds__(256) k0_convert(
    const float* __restrict__ x, const float* __restrict__ Win,
    const float* __restrict__ tau_m, const float* __restrict__ tau_n,
    uint8_t* __restrict__ xf8, uint8_t* __restrict__ wf8,
    unsigned* __restrict__ firstCross)
{
    __shared__ unsigned lds32[32 * 65];   // 8.3 KB
    const int i = blockIdx.x;             // 0..1023 x-blocks, 1024..1055 W-blocks
    const int t = threadIdx.x;

    const float* src;
    uint8_t* dstBase;
    int kqStride;
    if (i < 1024) {
        src = x + (size_t)(i * 32) * 256;
        dstBase = xf8 + (size_t)(i >> 2) * 32768 + (i & 3) * 2 * 512;
        kqStride = 4096;
    } else {
        const int i2 = i - 1024;
        src = Win + (size_t)(i2 * 32) * 256;
        dstBase = wf8 + (size_t)(i2 >> 1) * 16384 + (i2 & 1) * 2 * 512;
        kqStride = 2048;
    }

#pragma unroll
    for (int j = 0; j < 8; ++j) {
        const int f = j * 256 + t;
        const int lrow = f >> 6, c4 = f & 63;
        float4 v = *(const float4*)(src + (size_t)lrow * 256 + c4 * 4);
        int w0 = 0;
        w0 = __builtin_amdgcn_cvt_pk_fp8_f32(v.x, v.y, w0, false);
        w0 = __builtin_amdgcn_cvt_pk_fp8_f32(v.z, v.w, w0, true);
        lds32[lrow * 65 + c4] = (unsigned)w0;
    }
    __syncthreads();

#pragma unroll
    for (int j = 0; j < 2; ++j) {
        const int c = j * 256 + t;
        const int kq  = c >> 6;
        const int rbl = (c >> 5) & 1;
        const int l0  = (c & 31) * 2;
        const int r   = l0 & 15;
        const int q   = l0 >> 4;
        const int lrow = rbl * 16 + r;
        const int c0 = kq * 8 + q * 2;
        uint4 o;
        o.x = lds32[lrow * 65 + c0];
        o.y = lds32[lrow * 65 + c0 + 1];
        o.z = lds32[(lrow + 1) * 65 + c0];
        o.w = lds32[(lrow + 1) * 65 + c0 + 1];
        *(uint4*)(dstBase + kq * kqStride + rbl * 512 + l0 * 8) = o;
    }

    if (i == 0) {                         // block-uniform branch
        if (t < 64) firstCross[t] = 0xFFFFFFFFu;
        __syncthreads();
        bool bad = false;
        for (int j = t; j < H_; j += 256) {
            float a  = 1.f / (1.f + expf(-tau_m[j]));
            float be = 1.f / (1.f + expf(-tau_n[j]));
            float g  = fmaxf(a, be);
            float bound = __powf(g, 64.f) * (1.f + 64.f * (1.f - g)) * 8.f;
            if (!(bound < 0.1f) || !(g < 1.f) || !(g >= 0.f)) bad = true;
        }
        if (bad)
            for (int b2 = 0; b2 < 64; ++b2) firstCross[b2] = 0u;
    }
}

// ---- K1G: pure fp8 GEMM, ff (no bias) -> bf16 [b][h][t] -------------------
// 4096 blocks = (T: 256 t-tiles of 128) x (hn: 16 h-tiles of 64). 4 waves,
// each 32t x 64h (acc 2x4). B-slice (16 KB) staged once via DMA; A fragments
// loaded straight from global in k0's per-lane order (all 16 hoisted).
__global__ void __launch_bounds__(256) k1_gemm(
    const uint8_t* __restrict__ xf8, const uint8_t* __restrict__ wf8,
    unsigned short* __restrict__ ffb)
{
    __shared__ uint8_t lB[16384];

    const int tid  = threadIdx.x;
    const int w    = tid >> 6;
    const int lane = tid & 63;
    const int hn   = blockIdx.x & 15;
    const int T    = blockIdx.x >> 4;          // b*4 + tt
    const int colrow = lane & 15;
    const int quad   = lane >> 4;

    const uint8_t* gB = wf8 + (size_t)hn * 16384;
#pragma unroll
    for (int j = 0; j < 4; ++j) {
        const int off = (w * 4 + j) * 1024 + lane * 16;
        __builtin_amdgcn_global_load_lds(
            (const __attribute__((address_space(1))) void*)(gB + off),
            (__attribute__((address_space(3))) void*)(lB + off), 16, 0, 0);
    }
    __syncthreads();

    const uint8_t* xA = xf8 + (size_t)T * 32768 + w * 1024 + lane * 8;
    long long a[16];
#pragma unroll
    for (int kq = 0; kq < 8; ++kq) {
        a[kq * 2]     = *(const long long*)(xA + kq * 4096);
        a[kq * 2 + 1] = *(const long long*)(xA + kq * 4096 + 512);
    }

    f32x4 acc[2][4];
#pragma unroll
    for (int mi = 0; mi < 2; ++mi)
#pragma unroll
        for (int ni = 0; ni < 4; ++ni)
            acc[mi][ni] = (f32x4){0.f, 0.f, 0.f, 0.f};

#pragma unroll
    for (int kq = 0; kq < 8; ++kq) {
        long long bfr[4];
#pragma unroll
        for (int ni = 0; ni < 4; ++ni)
            bfr[ni] = *(const long long*)(lB + kq * 2048 + ni * 512 + lane * 8);
#pragma unroll
        for (int mi = 0; mi < 2; ++mi)
#pragma unroll
            for (int ni = 0; ni < 4; ++ni)
                acc[mi][ni] = __builtin_amdgcn_mfma_f32_16x16x32_fp8_fp8(
                    a[kq * 2 + mi], bfr[ni], acc[mi][ni], 0, 0, 0);
    }

    // store: value(t = tbase + mi*16 + r, h = hbase + ni*16 + colrow);
    // [b][h][t] layout -> acc r0..r3 are t-contiguous: one b64 store each.
    const size_t hbase = (size_t)(T >> 2) * 1024 + hn * 64;
    const int tbase = (T & 3) * 128 + w * 32 + quad * 4;
#pragma unroll
    for (int mi = 0; mi < 2; ++mi)
#pragma unroll
        for (int ni = 0; ni < 4; ++ni) {
            u16x4 p;
            p[0] = f2bf(acc[mi][ni][0]);
            p[1] = f2bf(acc[mi][ni][1]);
            p[2] = f2bf(acc[mi][ni][2]);
            p[3] = f2bf(acc[mi][ni][3]);
            *(u16x4*)(ffb + (hbase + ni * 16 + colrow) * 512
                          + tbase + mi * 16) = p;
        }
}

// ---- KS: chunk-parallel speculative scan with 64-step warmup --------------
// 1024 blocks = b(64) x hg(4) x c(4). Thread owns one h; chunk c scans
// t in [c*128-64, c*128+128) (c=0: exact from t=0), checks only the real
// 128 steps. Flags batch if mem > 0.9 or |tot| > 8 (sound given k0's guard).
__global__ void __launch_bounds__(256) ks_scan(
    const unsigned short* __restrict__ ffb,
    const float* __restrict__ b_in, const float* __restrict__ b_rec,
    const float* __restrict__ tau_m, const float* __restrict__ tau_n,
    unsigned* __restrict__ firstCross)
{
    const int tid = threadIdx.x;
    const int idx = blockIdx.x;
    const int c  = idx & 3;
    const int hg = (idx >> 2) & 3;
    const int b  = idx >> 4;
    const int h  = hg * 256 + tid;

    const float alpha = 1.f / (1.f + expf(-tau_m[h]));
    const float beta  = 1.f / (1.f + expf(-tau_n[h]));
    const float oma = 1.f - alpha, omb = 1.f - beta;
    const float bsum = b_in[h] + b_rec[h];

    const int t0     = (c == 0) ? 0 : (c * 128 - 64);
    const int nsteps = (c == 0) ? 128 : 192;
    const int ckFrom = (c == 0) ? 0 : 64;

    const unsigned short* p = ffb + ((size_t)b * 1024 + h) * 512 + t0;
    float d = 0.f, mem = 0.f;
    bool flag = false;
    for (int s = 0; s < nsteps; s += 8) {
        u16x8 v = *(const u16x8*)(p + s);
        const bool chk = (s >= ckFrom);
#pragma unroll
        for (int u = 0; u < 8; ++u) {
            const float tot = bf2f(v[u]) + bsum;
            d   = fmaf(beta,  d,   omb * tot);
            mem = fmaf(alpha, mem, oma * d);
            if (chk && (mem > 0.9f || fabsf(tot) > 8.f)) flag = true;
        }
    }
    if (__ballot(flag)) {
        if ((tid & 63) == 0) atomicMin(firstCross + b, 0u);
    }
}

// ---- K3: exact repair + output for spiking batches (runs ~never) ----------
__global__ void __launch_bounds__(1024) k3_repair(
    const float* __restrict__ x, const float* __restrict__ W_in,
    const float* __restrict__ b_in,
    const float* __restrict__ W_rec, const float* __restrict__ b_rec,
    const float* __restrict__ tau_m, const float* __restrict__ tau_n,
    const float* __restrict__ W_out, const float* __restrict__ b_out,
    const unsigned* __restrict__ firstCross,
    unsigned long long* __restrict__ gmask,
    float* __restrict__ out)
{
    const int b = blockIdx.x;
    if (firstCross[b] == 0xFFFFFFFFu) return;   // block-uniform
    const int h = threadIdx.x;
    __shared__ float xrow[I_];
    __shared__ unsigned long long msk[16];
    if (h < 16) msk[h] = 0ull;
    const float alpha = 1.f / (1.f + expf(-tau_m[h]));
    const float beta  = 1.f / (1.f + expf(-tau_n[h]));
    const float bsum  = b_in[h] + b_rec[h];
    const float* wi = W_in + (size_t)h * I_;
    const float* wr = W_rec + (size_t)h * H_;
    float d = 0.f, mem = 0.f;
    for (int t = 0; t < S_; ++t) {
        __syncthreads();
        if (h < I_) xrow[h] = x[((size_t)b * S_ + t) * I_ + h];
        __syncthreads();
        float ffv = 0.f;
        for (int k = 0; k < I_; ++k) ffv += xrow[k] * wi[k];
        float rec = 0.f;
#pragma unroll
        for (int wd = 0; wd < 16; ++wd) {
            unsigned long long mw = msk[wd];
            while (mw) {
                int bit = __ffsll((long long)mw) - 1;
                rec += wr[(wd << 6) + bit];
                mw &= (mw - 1);
            }
        }
        float tot = ffv + bsum + rec;
        d   = beta  * d   + (1.f - beta)  * tot;
        mem = alpha * mem + (1.f - alpha) * d;
        int sp = (mem > 1.0f) ? 1 : 0;
        if (sp) mem = 0.f;
        unsigned long long bal = __ballot(sp);
        __syncthreads();
        if ((h & 63) == 0) {
            msk[h >> 6] = bal;
            gmask[((size_t)b * S_ + t) * 16 + (h >> 6)] = bal;
        }
    }
    __syncthreads();
    __threadfence_block();
    for (int i = h; i < S_ * O_; i += 1024) {
        const int t = i >> 7, o = i & (O_ - 1);
        float logit = b_out[o];
        const unsigned long long* m = gmask + ((size_t)b * S_ + t) * 16;
        const float* wo = W_out + (size_t)o * H_;
        for (int wd = 0; wd < 16; ++wd) {
            unsigned long long mw = m[wd];
            while (mw) {
                int bit = __ffsll((long long)mw) - 1;
                logit += wo[(wd << 6) + bit];
                mw &= (mw - 1);
            }
        }
        out[((size_t)b * S_ + t) * O_ + o] = 1.f / (1.f + expf(-logit));
    }
}

// ---- K4: fast-path output for non-spiking batches -------------------------
__global__ void __launch_bounds__(256) k4_out(
    const float* __restrict__ b_out,
    const unsigned* __restrict__ firstCross,
    float* __restrict__ out)
{
    const int i4 = blockIdx.x * 256 + threadIdx.x;   // float4 index
    const int b  = i4 >> 14;                         // 16384 float4 per batch
    if (firstCross[b] != 0xFFFFFFFFu) return;        // k3 owns this batch
    const int o4 = i4 & 31;
    float4 v = *(const float4*)(b_out + o4 * 4);
    float4 r;
    r.x = 1.f / (1.f + expf(-v.x));
    r.y = 1.f / (1.f + expf(-v.y));
    r.z = 1.f / (1.f + expf(-v.z));
    r.w = 1.f / (1.f + expf(-v.w));
    *(float4*)(out + (size_t)i4 * 4) = r;
}

extern "C" void kernel_launch(void* const* d_in, const int* in_sizes, int n_in,
                              void* d_out, int out_size, void* d_ws, size_t ws_size,
                              hipStream_t stream) {
    const float* x     = (const float*)d_in[0];
    const float* W_in  = (const float*)d_in[1];
    const float* b_in  = (const float*)d_in[2];
    const float* W_rec = (const float*)d_in[3];
    const float* b_rec = (const float*)d_in[4];
    const float* tau_m = (const float*)d_in[5];
    const float* tau_n = (const float*)d_in[6];
    const float* W_out = (const float*)d_in[7];
    const float* b_out = (const float*)d_in[8];
    float* out = (float*)d_out;

    char* ws = (char*)d_ws;
    size_t off = 0;
    uint8_t* xf8 = (uint8_t*)(ws + off);               off += (size_t)M_ * I_;        // 8 MB
    uint8_t* wf8 = (uint8_t*)(ws + off);               off += (size_t)H_ * I_;        // 256 KB
    unsigned short* ffb = (unsigned short*)(ws + off); off += (size_t)M_ * H_ * 2;    // 64 MB
    unsigned long long* gmask = (unsigned long long*)(ws + off); off += (size_t)B_ * S_ * 16 * 8; // 4 MB
    unsigned* firstCross = (unsigned*)(ws + off);      off += 256;
    if (ws_size < off) return;

    k0_convert<<<1056, 256, 0, stream>>>(x, W_in, tau_m, tau_n, xf8, wf8, firstCross);
    k1_gemm<<<4096, 256, 0, stream>>>(xf8, wf8, ffb);
    ks_scan<<<1024, 256, 0, stream>>>(ffb, b_in, b_rec, tau_m, tau_n, firstCross);
    k3_repair<<<64, 1024, 0, stream>>>(x, W_in, b_in, W_rec, b_rec, tau_m, tau_n,
                                       W_out, b_out, firstCross, gmask, out);
    k4_out<<<4096, 256, 0, stream>>>(b_out, firstCross, out);
}

// Round 9
// 157.832 us; speedup vs baseline: 1.0625x; 1.0625x over previous
//
#include <hip/hip_runtime.h>
#include <hip/hip_bf16.h>
#include <stdint.h>

#define B_ 64
#define S_ 512
#define I_ 256
#define H_ 1024
#define O_ 128
#define M_ (B_*S_)   // 32768

typedef float f32x4 __attribute__((ext_vector_type(4)));
typedef unsigned short u16x4 __attribute__((ext_vector_type(4)));

__device__ __forceinline__ unsigned short f2bf(float f) {
    unsigned u = __float_as_uint(f);
    u += 0x7FFFu + ((u >> 16) & 1u);
    return (unsigned short)(u >> 16);
}
__device__ __forceinline__ float bf2f(unsigned short s) {
    return __uint_as_float((unsigned)s << 16);
}

// ---- K0: fp32 -> fp8 e4m3 into per-lane fragment order, via LDS transpose.
// A region: [tile128][kq(8)][rb(8)][lane*8B]; B: [hn(16)][kq(8)][rb(4)][lane*8B].
// Fragment: lane l holds row rb*16+(l&15), k = kq*32+(l>>4)*8..+8.
// Block 0 also inits firstCross and applies the tau-paranoia guard (forces the
// exact k3 path for all batches if the EMA decay is too slow for the 64-step
// warmup bound; never fires for tau=2 -> gamma=0.881, bound~0.02).
__global__ void __launch_bounds__(256) k0_convert(
    const float* __restrict__ x, const float* __restrict__ Win,
    const float* __restrict__ tau_m, const float* __restrict__ tau_n,
    uint8_t* __restrict__ xf8, uint8_t* __restrict__ wf8,
    unsigned* __restrict__ firstCross)
{
    __shared__ unsigned lds32[32 * 65];   // 8.3 KB
    const int i = blockIdx.x;             // 0..1023 x-blocks, 1024..1055 W-blocks
    const int t = threadIdx.x;

    const float* src;
    uint8_t* dstBase;
    int kqStride;
    if (i < 1024) {
        src = x + (size_t)(i * 32) * 256;
        dstBase = xf8 + (size_t)(i >> 2) * 32768 + (i & 3) * 2 * 512;
        kqStride = 4096;
    } else {
        const int i2 = i - 1024;
        src = Win + (size_t)(i2 * 32) * 256;
        dstBase = wf8 + (size_t)(i2 >> 1) * 16384 + (i2 & 1) * 2 * 512;
        kqStride = 2048;
    }

#pragma unroll
    for (int j = 0; j < 8; ++j) {
        const int f = j * 256 + t;
        const int lrow = f >> 6, c4 = f & 63;
        float4 v = *(const float4*)(src + (size_t)lrow * 256 + c4 * 4);
        int w0 = 0;
        w0 = __builtin_amdgcn_cvt_pk_fp8_f32(v.x, v.y, w0, false);
        w0 = __builtin_amdgcn_cvt_pk_fp8_f32(v.z, v.w, w0, true);
        lds32[lrow * 65 + c4] = (unsigned)w0;
    }
    __syncthreads();

#pragma unroll
    for (int j = 0; j < 2; ++j) {
        const int c = j * 256 + t;
        const int kq  = c >> 6;
        const int rbl = (c >> 5) & 1;
        const int l0  = (c & 31) * 2;
        const int r   = l0 & 15;
        const int q   = l0 >> 4;
        const int lrow = rbl * 16 + r;
        const int c0 = kq * 8 + q * 2;
        uint4 o;
        o.x = lds32[lrow * 65 + c0];
        o.y = lds32[lrow * 65 + c0 + 1];
        o.z = lds32[(lrow + 1) * 65 + c0];
        o.w = lds32[(lrow + 1) * 65 + c0 + 1];
        *(uint4*)(dstBase + kq * kqStride + rbl * 512 + l0 * 8) = o;
    }

    if (i == 0) {
        if (t < 64) firstCross[t] = 0xFFFFFFFFu;
        __syncthreads();
        bool bad = false;
        for (int j = t; j < H_; j += 256) {
            float a  = 1.f / (1.f + expf(-tau_m[j]));
            float be = 1.f / (1.f + expf(-tau_n[j]));
            float g  = fmaxf(a, be);
            float bound = __powf(g, 64.f) * (1.f + 64.f * (1.f - g)) * 8.f;
            if (!(bound < 0.1f) || !(g < 1.f) || !(g >= 0.f)) bad = true;
        }
        if (bad)
            for (int b2 = 0; b2 < 64; ++b2) firstCross[b2] = 0u;
    }
}

// ---- K1: fp8 GEMM, x read ONCE, ff -> bf16 [b][t][h] ----------------------
// 512 blocks = (T: 256 t-tiles of 128) x (hhalf: 2). hn loops INSIDE the
// block with A-fragments register-resident, so each x tile is fetched once.
// W-frags read straight from L2 (256KB, hot per XCD). No LDS, no barriers.
__global__ void __launch_bounds__(256) k1_gemm(
    const uint8_t* __restrict__ xf8, const uint8_t* __restrict__ wf8,
    unsigned short* __restrict__ ffb)
{
    const int tid  = threadIdx.x;
    const int w    = tid >> 6;
    const int lane = tid & 63;
    const int T    = blockIdx.x >> 1;          // b*4 + tt
    const int hh   = blockIdx.x & 1;
    const int colrow = lane & 15;
    const int quad   = lane >> 4;
    const int b  = T >> 2;
    const int tt = T & 3;

    // A fragments for this wave's 32-t band: 16 x 8B, resident for all hn
    const uint8_t* xA = xf8 + (size_t)T * 32768 + w * 1024 + lane * 8;
    long long a[16];
#pragma unroll
    for (int kq = 0; kq < 8; ++kq) {
        a[kq * 2]     = *(const long long*)(xA + kq * 4096);
        a[kq * 2 + 1] = *(const long long*)(xA + kq * 4096 + 512);
    }

    const int tbase = tt * 128 + w * 32 + quad * 4;
    unsigned short* dst0 = ffb + ((size_t)b * 512 + tbase) * 1024 + colrow;

    for (int j = 0; j < 8; ++j) {
        const int hn = hh * 8 + j;
        const uint8_t* wB = wf8 + (size_t)hn * 16384 + lane * 8;

        f32x4 acc[2][4];
#pragma unroll
        for (int mi = 0; mi < 2; ++mi)
#pragma unroll
            for (int ni = 0; ni < 4; ++ni)
                acc[mi][ni] = (f32x4){0.f, 0.f, 0.f, 0.f};

#pragma unroll
        for (int kq = 0; kq < 8; ++kq) {
            long long bfr[4];
#pragma unroll
            for (int ni = 0; ni < 4; ++ni)
                bfr[ni] = *(const long long*)(wB + kq * 2048 + ni * 512);
#pragma unroll
            for (int mi = 0; mi < 2; ++mi)
#pragma unroll
                for (int ni = 0; ni < 4; ++ni)
                    acc[mi][ni] = __builtin_amdgcn_mfma_f32_16x16x32_fp8_fp8(
                        a[kq * 2 + mi], bfr[ni], acc[mi][ni], 0, 0, 0);
        }

        // store to [b][t][h]: value(t = tbase + mi*16 + r, h = hn*64 + ni*16 + colrow)
        unsigned short* dst = dst0 + hn * 64;
#pragma unroll
        for (int mi = 0; mi < 2; ++mi)
#pragma unroll
            for (int ni = 0; ni < 4; ++ni)
#pragma unroll
                for (int r = 0; r < 4; ++r)
                    dst[(size_t)(mi * 16 + r) * 1024 + ni * 16] =
                        f2bf(acc[mi][ni][r]);
    }
}

// ---- KS: chunk-parallel scan, coalesced h-major streaming -----------------
// 512 blocks = b(64) x c(8). 256 threads x 4 consecutive h = 1024 h (exact,
// in-bounds). Chunk c covers real t in [c*64, c*64+64), warmed up from
// t = c*64-64 (c=0: exact from 0). Per t the block reads one full 2KB h-row
// (8B/lane, coalesced); 4 independent chains/thread for FMA ILP.
__global__ void __launch_bounds__(256) ks_scan(
    const unsigned short* __restrict__ ffb,
    const float* __restrict__ b_in, const float* __restrict__ b_rec,
    const float* __restrict__ tau_m, const float* __restrict__ tau_n,
    unsigned* __restrict__ firstCross)
{
    const int tid = threadIdx.x;
    const int c   = blockIdx.x & 7;
    const int b   = blockIdx.x >> 3;
    const int h0  = tid * 4;          // 0..1020

    float al[4], be[4], oma[4], omb[4], bs[4], d[4], mem[4];
#pragma unroll
    for (int q = 0; q < 4; ++q) {
        const int h = h0 + q;
        al[q] = 1.f / (1.f + expf(-tau_m[h]));
        be[q] = 1.f / (1.f + expf(-tau_n[h]));
        oma[q] = 1.f - al[q]; omb[q] = 1.f - be[q];
        bs[q] = b_in[h] + b_rec[h];
        d[q] = 0.f; mem[q] = 0.f;
    }

    const int t0     = (c == 0) ? 0 : (c * 64 - 64);
    const int nsteps = (c == 0) ? 64 : 128;
    const int ckFrom = (c == 0) ? 0 : 64;

    const unsigned short* p = ffb + ((size_t)b * 512 + t0) * 1024 + h0;
    bool flag = false;
    for (int s = 0; s < nsteps; s += 4) {
        u16x4 v[4];
#pragma unroll
        for (int k = 0; k < 4; ++k)
            v[k] = *(const u16x4*)(p + (size_t)(s + k) * 1024);
        const bool chk = (s >= ckFrom);
#pragma unroll
        for (int k = 0; k < 4; ++k)
#pragma unroll
            for (int q = 0; q < 4; ++q) {
                const float tot = bf2f(v[k][q]) + bs[q];
                d[q]   = fmaf(be[q], d[q],   omb[q] * tot);
                mem[q] = fmaf(al[q], mem[q], oma[q] * d[q]);
                if (chk && (mem[q] > 0.9f || fabsf(tot) > 8.f)) flag = true;
            }
    }
    if (__ballot(flag)) {
        if ((tid & 63) == 0) atomicMin(firstCross + b, 0u);
    }
}

// ---- K3: exact repair + output for spiking batches (runs ~never) ----------
__global__ void __launch_bounds__(1024) k3_repair(
    const float* __restrict__ x, const float* __restrict__ W_in,
    const float* __restrict__ b_in,
    const float* __restrict__ W_rec, const float* __restrict__ b_rec,
    const float* __restrict__ tau_m, const float* __restrict__ tau_n,
    const float* __restrict__ W_out, const float* __restrict__ b_out,
    const unsigned* __restrict__ firstCross,
    unsigned long long* __restrict__ gmask,
    float* __restrict__ out)
{
    const int b = blockIdx.x;
    if (firstCross[b] == 0xFFFFFFFFu) return;   // block-uniform
    const int h = threadIdx.x;
    __shared__ float xrow[I_];
    __shared__ unsigned long long msk[16];
    if (h < 16) msk[h] = 0ull;
    const float alpha = 1.f / (1.f + expf(-tau_m[h]));
    const float beta  = 1.f / (1.f + expf(-tau_n[h]));
    const float bsum  = b_in[h] + b_rec[h];
    const float* wi = W_in + (size_t)h * I_;
    const float* wr = W_rec + (size_t)h * H_;
    float d = 0.f, mem = 0.f;
    for (int t = 0; t < S_; ++t) {
        __syncthreads();
        if (h < I_) xrow[h] = x[((size_t)b * S_ + t) * I_ + h];
        __syncthreads();
        float ffv = 0.f;
        for (int k = 0; k < I_; ++k) ffv += xrow[k] * wi[k];
        float rec = 0.f;
#pragma unroll
        for (int wd = 0; wd < 16; ++wd) {
            unsigned long long mw = msk[wd];
            while (mw) {
                int bit = __ffsll((long long)mw) - 1;
                rec += wr[(wd << 6) + bit];
                mw &= (mw - 1);
            }
        }
        float tot = ffv + bsum + rec;
        d   = beta  * d   + (1.f - beta)  * tot;
        mem = alpha * mem + (1.f - alpha) * d;
        int sp = (mem > 1.0f) ? 1 : 0;
        if (sp) mem = 0.f;
        unsigned long long bal = __ballot(sp);
        __syncthreads();
        if ((h & 63) == 0) {
            msk[h >> 6] = bal;
            gmask[((size_t)b * S_ + t) * 16 + (h >> 6)] = bal;
        }
    }
    __syncthreads();
    __threadfence_block();
    for (int i = h; i < S_ * O_; i += 1024) {
        const int t = i >> 7, o = i & (O_ - 1);
        float logit = b_out[o];
        const unsigned long long* m = gmask + ((size_t)b * S_ + t) * 16;
        const float* wo = W_out + (size_t)o * H_;
        for (int wd = 0; wd < 16; ++wd) {
            unsigned long long mw = m[wd];
            while (mw) {
                int bit = __ffsll((long long)mw) - 1;
                logit += wo[(wd << 6) + bit];
                mw &= (mw - 1);
            }
        }
        out[((size_t)b * S_ + t) * O_ + o] = 1.f / (1.f + expf(-logit));
    }
}

// ---- K4: fast-path output for non-spiking batches -------------------------
__global__ void __launch_bounds__(256) k4_out(
    const float* __restrict__ b_out,
    const unsigned* __restrict__ firstCross,
    float* __restrict__ out)
{
    const int i4 = blockIdx.x * 256 + threadIdx.x;   // float4 index
    const int b  = i4 >> 14;                         // 16384 float4 per batch
    if (firstCross[b] != 0xFFFFFFFFu) return;        // k3 owns this batch
    const int o4 = i4 & 31;
    float4 v = *(const float4*)(b_out + o4 * 4);
    float4 r;
    r.x = 1.f / (1.f + expf(-v.x));
    r.y = 1.f / (1.f + expf(-v.y));
    r.z = 1.f / (1.f + expf(-v.z));
    r.w = 1.f / (1.f + expf(-v.w));
    *(float4*)(out + (size_t)i4 * 4) = r;
}

extern "C" void kernel_launch(void* const* d_in, const int* in_sizes, int n_in,
                              void* d_out, int out_size, void* d_ws, size_t ws_size,
                              hipStream_t stream) {
    const float* x     = (const float*)d_in[0];
    const float* W_in  = (const float*)d_in[1];
    const float* b_in  = (const float*)d_in[2];
    const float* W_rec = (const float*)d_in[3];
    const float* b_rec = (const float*)d_in[4];
    const float* tau_m = (const float*)d_in[5];
    const float* tau_n = (const float*)d_in[6];
    const float* W_out = (const float*)d_in[7];
    const float* b_out = (const float*)d_in[8];
    float* out = (float*)d_out;

    char* ws = (char*)d_ws;
    size_t off = 0;
    uint8_t* xf8 = (uint8_t*)(ws + off);               off += (size_t)M_ * I_;        // 8 MB
    uint8_t* wf8 = (uint8_t*)(ws + off);               off += (size_t)H_ * I_;        // 256 KB
    unsigned short* ffb = (unsigned short*)(ws + off); off += (size_t)M_ * H_ * 2;    // 64 MB
    unsigned long long* gmask = (unsigned long long*)(ws + off); off += (size_t)B_ * S_ * 16 * 8; // 4 MB
    unsigned* firstCross = (unsigned*)(ws + off);      off += 256;
    if (ws_size < off) return;

    k0_convert<<<1056, 256, 0, stream>>>(x, W_in, tau_m, tau_n, xf8, wf8, firstCross);
    k1_gemm<<<512, 256, 0, stream>>>(xf8, wf8, ffb);
    ks_scan<<<512, 256, 0, stream>>>(ffb, b_in, b_rec, tau_m, tau_n, firstCross);
    k3_repair<<<64, 1024, 0, stream>>>(x, W_in, b_in, W_rec, b_rec, tau_m, tau_n,
                                       W_out, b_out, firstCross, gmask, out);
    k4_out<<<4096, 256, 0, stream>>>(b_out, firstCross, out);
}

// Round 10
// 150.125 us; speedup vs baseline: 1.1170x; 1.0513x over previous
//
#include <hip/hip_runtime.h>
#include <hip/hip_bf16.h>
#include <stdint.h>

#define B_ 64
#define S_ 512
#define I_ 256
#define H_ 1024
#define O_ 128
#define M_ (B_*S_)   // 32768
#define ST_ 1032     // lS h-stride bytes: 8B-aligned, bank-stride 2 -> 4-way max

typedef float f32x4 __attribute__((ext_vector_type(4)));
typedef unsigned short u16x4 __attribute__((ext_vector_type(4)));

__device__ __forceinline__ unsigned short f2bf(float f) {
    unsigned u = __float_as_uint(f);
    u += 0x7FFFu + ((u >> 16) & 1u);
    return (unsigned short)(u >> 16);
}
__device__ __forceinline__ float bf2f(unsigned short s) {
    return __uint_as_float((unsigned)s << 16);
}

// ---- K0: fp32 -> fp8 e4m3 into per-lane fragment order, via LDS transpose.
// A region: [tile128][kq(8)][rb(8)][lane*8B]; B: [hn(16)][kq(8)][rb(4)][lane*8B].
// Fragment: lane l holds row rb*16+(l&15), k = kq*32+(l>>4)*8..+8.
// Block 0 also inits firstCross/cnt and applies the tau-paranoia guard.
__global__ void __launch_bounds__(256) k0_convert(
    const float* __restrict__ x, const float* __restrict__ Win,
    const float* __restrict__ tau_m, const float* __restrict__ tau_n,
    uint8_t* __restrict__ xf8, uint8_t* __restrict__ wf8,
    unsigned* __restrict__ firstCross, unsigned* __restrict__ cnt)
{
    __shared__ unsigned lds32[32 * 65];   // 8.3 KB
    const int i = blockIdx.x;             // 0..1023 x-blocks, 1024..1055 W-blocks
    const int t = threadIdx.x;

    const float* src;
    uint8_t* dstBase;
    int kqStride;
    if (i < 1024) {
        src = x + (size_t)(i * 32) * 256;
        dstBase = xf8 + (size_t)(i >> 2) * 32768 + (i & 3) * 2 * 512;
        kqStride = 4096;
    } else {
        const int i2 = i - 1024;
        src = Win + (size_t)(i2 * 32) * 256;
        dstBase = wf8 + (size_t)(i2 >> 1) * 16384 + (i2 & 1) * 2 * 512;
        kqStride = 2048;
    }

#pragma unroll
    for (int j = 0; j < 8; ++j) {
        const int f = j * 256 + t;
        const int lrow = f >> 6, c4 = f & 63;
        float4 v = *(const float4*)(src + (size_t)lrow * 256 + c4 * 4);
        int w0 = 0;
        w0 = __builtin_amdgcn_cvt_pk_fp8_f32(v.x, v.y, w0, false);
        w0 = __builtin_amdgcn_cvt_pk_fp8_f32(v.z, v.w, w0, true);
        lds32[lrow * 65 + c4] = (unsigned)w0;
    }
    __syncthreads();

#pragma unroll
    for (int j = 0; j < 2; ++j) {
        const int c = j * 256 + t;
        const int kq  = c >> 6;
        const int rbl = (c >> 5) & 1;
        const int l0  = (c & 31) * 2;
        const int r   = l0 & 15;
        const int q   = l0 >> 4;
        const int lrow = rbl * 16 + r;
        const int c0 = kq * 8 + q * 2;
        uint4 o;
        o.x = lds32[lrow * 65 + c0];
        o.y = lds32[lrow * 65 + c0 + 1];
        o.z = lds32[(lrow + 1) * 65 + c0];
        o.w = lds32[(lrow + 1) * 65 + c0 + 1];
        *(uint4*)(dstBase + kq * kqStride + rbl * 512 + l0 * 8) = o;
    }

    if (i == 0) {
        if (t < 64) firstCross[t] = 0xFFFFFFFFu;
        else if (t < 128) cnt[t - 64] = 0u;
        __syncthreads();
        bool bad = false;
        for (int j = t; j < H_; j += 256) {
            float a  = 1.f / (1.f + expf(-tau_m[j]));
            float be = 1.f / (1.f + expf(-tau_n[j]));
            float g  = fmaxf(a, be);
            float bound = __powf(g, 64.f) * (1.f + 64.f * (1.f - g)) * 8.f;
            if (!(bound < 0.1f) || !(g < 1.f) || !(g >= 0.f)) bad = true;
        }
        if (bad)
            for (int b2 = 0; b2 < 64; ++b2) atomicMin(firstCross + b2, 0u);
    }
}

// ---- KF: fused fp8 GEMM (no inter-tile barriers) + chunk-parallel in-LDS
// scan + last-block-per-batch output. 1024 blocks = b(64) x hn(16), 256 thr.
// GEMM: 4 t-tiles back-to-back, dumps to full 64h x 512t bf16 lS (66 KB);
// ONE barrier; scan: thread (h = tid&63, chunk c = tid>>6) covers real
// t in [c*128, c*128+128) warmed from c*128-64 (c=0 exact).
__global__ void __launch_bounds__(256) kf_gemm_scan(
    const uint8_t* __restrict__ xf8, const uint8_t* __restrict__ wf8,
    const float* __restrict__ b_in, const float* __restrict__ b_rec,
    const float* __restrict__ tau_m, const float* __restrict__ tau_n,
    const float* __restrict__ b_out,
    unsigned* __restrict__ firstCross, unsigned* __restrict__ cnt,
    float* __restrict__ out)
{
    __shared__ uint8_t lS[64 * ST_];   // 66 KB: offset = h*ST_ + (T>>3)*16 + (T&7)*2
    __shared__ int lastFlag;

    const int tid  = threadIdx.x;
    const int w    = tid >> 6;
    const int lane = tid & 63;
    const int idx  = blockIdx.x;
    const int b    = (idx & 7) | ((idx >> 7) << 3);   // XCD swizzle
    const int hn   = (idx >> 3) & 15;
    const int colrow = lane & 15;
    const int quad   = lane >> 4;

    // B fragments, register-resident: 32 x 8B
    const uint8_t* wB = wf8 + (size_t)hn * 16384 + lane * 8;
    long long bq[32];
#pragma unroll
    for (int kq = 0; kq < 8; ++kq)
#pragma unroll
        for (int ni = 0; ni < 4; ++ni)
            bq[kq * 4 + ni] = *(const long long*)(wB + kq * 2048 + ni * 512);

    for (int tt = 0; tt < 4; ++tt) {
        const uint8_t* xA = xf8 + (size_t)(b * 4 + tt) * 32768
                          + w * 1024 + lane * 8;
        long long a[16];
#pragma unroll
        for (int kq = 0; kq < 8; ++kq) {
            a[kq * 2]     = *(const long long*)(xA + kq * 4096);
            a[kq * 2 + 1] = *(const long long*)(xA + kq * 4096 + 512);
        }
        f32x4 acc[2][4];
#pragma unroll
        for (int mi = 0; mi < 2; ++mi)
#pragma unroll
            for (int ni = 0; ni < 4; ++ni)
                acc[mi][ni] = (f32x4){0.f, 0.f, 0.f, 0.f};
#pragma unroll
        for (int kq = 0; kq < 8; ++kq)
#pragma unroll
            for (int mi = 0; mi < 2; ++mi)
#pragma unroll
                for (int ni = 0; ni < 4; ++ni)
                    acc[mi][ni] = __builtin_amdgcn_mfma_f32_16x16x32_fp8_fp8(
                        a[kq * 2 + mi], bq[kq * 4 + ni], acc[mi][ni], 0, 0, 0);

        // dump tile tt -> its region of lS (no barrier needed: sole writer)
#pragma unroll
        for (int mi = 0; mi < 2; ++mi) {
            const int T0 = tt * 128 + w * 32 + mi * 16 + quad * 4;
            const int gb = ((T0 >> 3) << 4) + ((T0 & 7) << 1);
#pragma unroll
            for (int ni = 0; ni < 4; ++ni) {
                const int h0 = ni * 16 + colrow;
                u16x4 p;
                p[0] = f2bf(acc[mi][ni][0]);
                p[1] = f2bf(acc[mi][ni][1]);
                p[2] = f2bf(acc[mi][ni][2]);
                p[3] = f2bf(acc[mi][ni][3]);
                *(u16x4*)(lS + h0 * ST_ + gb) = p;
            }
        }
    }
    __syncthreads();   // the only barrier: all tiles dumped

    // chunk-parallel scan: h = tid&63, chunk c = tid>>6 (per-wave uniform)
    {
        const int h = tid & 63;
        const int c = tid >> 6;
        const int hs = hn * 64 + h;
        const float alpha = 1.f / (1.f + expf(-tau_m[hs]));
        const float beta  = 1.f / (1.f + expf(-tau_n[hs]));
        const float oma = 1.f - alpha, omb = 1.f - beta;
        const float bsum = b_in[hs] + b_rec[hs];

        const int t0     = (c == 0) ? 0 : (c * 128 - 64);
        const int nsteps = (c == 0) ? 128 : 192;
        const int ckFrom = (c == 0) ? 0 : 64;

        const uint8_t* row = lS + h * ST_;
        float d = 0.f, mem = 0.f;
        bool flag = false;
        for (int s = 0; s < nsteps; s += 4) {
            const int T = t0 + s;
            u16x4 v = *(const u16x4*)(row + ((T >> 3) << 4) + ((T & 7) << 1));
            const bool chk = (s >= ckFrom);
#pragma unroll
            for (int u = 0; u < 4; ++u) {
                const float tot = bf2f(v[u]) + bsum;
                d   = fmaf(beta,  d,   omb * tot);
                mem = fmaf(alpha, mem, oma * d);
                // sound flag: fp8-GEMM err<=0.13 + warmup 0.034 + bf16 0.016
                if (chk && (mem > 0.8f || fabsf(tot) > 8.f)) flag = true;
            }
        }
        if (__ballot(flag)) {
            if (lane == 0) atomicMin(firstCross + b, 0u);
        }
    }

    __syncthreads();
    if (tid == 0) {
        __threadfence();                       // release our atomicMins
        unsigned old = atomicAdd(cnt + b, 1u);
        int flag = 0;
        if (old == 15u) {                      // last of the 16 blocks for b
            __threadfence();                   // acquire
            unsigned fc = atomicAdd(firstCross + b, 0u);
            flag = (fc == 0xFFFFFFFFu) ? 1 : 0;
        }
        lastFlag = flag;
    }
    __syncthreads();
    if (lastFlag) {                            // block-uniform: no spikes in b
        float* sg = (float*)lS;
        if (tid < 128) sg[tid] = 1.f / (1.f + expf(-b_out[tid]));
        __syncthreads();
        const int q = tid & 31;
        float4 v = *(float4*)(sg + q * 4);
        float* obase = out + (size_t)b * (S_ * O_) + q * 4;
        const int trow = tid >> 5;
#pragma unroll 4
        for (int k = 0; k < 64; ++k)
            *(float4*)(obase + (size_t)(trow + k * 8) * O_) = v;
    }
}

// ---- K3: exact repair + output for spiking batches (runs ~never) ----------
__global__ void __launch_bounds__(1024) k3_repair(
    const float* __restrict__ x, const float* __restrict__ W_in,
    const float* __restrict__ b_in,
    const float* __restrict__ W_rec, const float* __restrict__ b_rec,
    const float* __restrict__ tau_m, const float* __restrict__ tau_n,
    const float* __restrict__ W_out, const float* __restrict__ b_out,
    const unsigned* __restrict__ firstCross,
    unsigned long long* __restrict__ gmask,
    float* __restrict__ out)
{
    const int b = blockIdx.x;
    if (firstCross[b] == 0xFFFFFFFFu) return;   // block-uniform
    const int h = threadIdx.x;
    __shared__ float xrow[I_];
    __shared__ unsigned long long msk[16];
    if (h < 16) msk[h] = 0ull;
    const float alpha = 1.f / (1.f + expf(-tau_m[h]));
    const float beta  = 1.f / (1.f + expf(-tau_n[h]));
    const float bsum  = b_in[h] + b_rec[h];
    const float* wi = W_in + (size_t)h * I_;
    const float* wr = W_rec + (size_t)h * H_;
    float d = 0.f, mem = 0.f;
    for (int t = 0; t < S_; ++t) {
        __syncthreads();
        if (h < I_) xrow[h] = x[((size_t)b * S_ + t) * I_ + h];
        __syncthreads();
        float ffv = 0.f;
        for (int k = 0; k < I_; ++k) ffv += xrow[k] * wi[k];
        float rec = 0.f;
#pragma unroll
        for (int wd = 0; wd < 16; ++wd) {
            unsigned long long mw = msk[wd];
            while (mw) {
                int bit = __ffsll((long long)mw) - 1;
                rec += wr[(wd << 6) + bit];
                mw &= (mw - 1);
            }
        }
        float tot = ffv + bsum + rec;
        d   = beta  * d   + (1.f - beta)  * tot;
        mem = alpha * mem + (1.f - alpha) * d;
        int sp = (mem > 1.0f) ? 1 : 0;
        if (sp) mem = 0.f;
        unsigned long long bal = __ballot(sp);
        __syncthreads();
        if ((h & 63) == 0) {
            msk[h >> 6] = bal;
            gmask[((size_t)b * S_ + t) * 16 + (h >> 6)] = bal;
        }
    }
    __syncthreads();
    __threadfence_block();
    for (int i = h; i < S_ * O_; i += 1024) {
        const int t = i >> 7, o = i & (O_ - 1);
        float logit = b_out[o];
        const unsigned long long* m = gmask + ((size_t)b * S_ + t) * 16;
        const float* wo = W_out + (size_t)o * H_;
        for (int wd = 0; wd < 16; ++wd) {
            unsigned long long mw = m[wd];
            while (mw) {
                int bit = __ffsll((long long)mw) - 1;
                logit += wo[(wd << 6) + bit];
                mw &= (mw - 1);
            }
        }
        out[((size_t)b * S_ + t) * O_ + o] = 1.f / (1.f + expf(-logit));
    }
}

extern "C" void kernel_launch(void* const* d_in, const int* in_sizes, int n_in,
                              void* d_out, int out_size, void* d_ws, size_t ws_size,
                              hipStream_t stream) {
    const float* x     = (const float*)d_in[0];
    const float* W_in  = (const float*)d_in[1];
    const float* b_in  = (const float*)d_in[2];
    const float* W_rec = (const float*)d_in[3];
    const float* b_rec = (const float*)d_in[4];
    const float* tau_m = (const float*)d_in[5];
    const float* tau_n = (const float*)d_in[6];
    const float* W_out = (const float*)d_in[7];
    const float* b_out = (const float*)d_in[8];
    float* out = (float*)d_out;

    char* ws = (char*)d_ws;
    size_t off = 0;
    uint8_t* xf8 = (uint8_t*)(ws + off);               off += (size_t)M_ * I_;        // 8 MB
    uint8_t* wf8 = (uint8_t*)(ws + off);               off += (size_t)H_ * I_;        // 256 KB
    unsigned long long* gmask = (unsigned long long*)(ws + off); off += (size_t)B_ * S_ * 16 * 8; // 4 MB
    unsigned* firstCross = (unsigned*)(ws + off);      off += 256;
    unsigned* cnt = (unsigned*)(ws + off);             off += 256;
    if (ws_size < off) return;

    k0_convert<<<1056, 256, 0, stream>>>(x, W_in, tau_m, tau_n, xf8, wf8,
                                         firstCross, cnt);
    kf_gemm_scan<<<1024, 256, 0, stream>>>(xf8, wf8, b_in, b_rec, tau_m, tau_n,
                                           b_out, firstCross, cnt, out);
    k3_repair<<<64, 1024, 0, stream>>>(x, W_in, b_in, W_rec, b_rec, tau_m, tau_n,
                                       W_out, b_out, firstCross, gmask, out);
}